// Round 1
// baseline (1425.961 us; speedup 1.0000x reference)
//
#include <hip/hip_runtime.h>
#include <math.h>

// Problem constants (hardcoded from reference)
#define B_ 2
#define S_ 8193
#define L_ 8192
#define E_ 512
#define H_ 8
#define D_ 64
#define QKV_COLS 1536   // 3*E
#define SCALE 0.125f    // 1/sqrt(64)

// ---------------------------------------------------------------------------
// GEMM: C[m,n] = sum_k A[m,k] * W[n,k] + bias[n]
// A: M x K row-major, W: N x K row-major (i.e. C = A @ W^T + bias)
// 64x64 tile, 256 threads, 4x4 per thread, BK=16.
// N, K assumed multiples of 64/16; M guarded.
// ---------------------------------------------------------------------------
#define TM 64
#define TN 64
#define TK 16

__global__ __launch_bounds__(256) void gemm_nt_bias(
    const float* __restrict__ A,
    const float* __restrict__ W,
    const float* __restrict__ bias,
    float* __restrict__ C,
    int M, int N, int K)
{
    __shared__ float As[TM][TK + 1];
    __shared__ float Ws[TN][TK + 1];

    const int tid = threadIdx.x;
    const int tx = tid % 16;   // n-direction
    const int ty = tid / 16;   // m-direction
    const int m0 = blockIdx.y * TM;
    const int n0 = blockIdx.x * TN;

    // loader: each thread loads one float4 per tile per matrix
    const int lrow = tid >> 2;        // 0..63
    const int lcol = (tid & 3) * 4;   // 0,4,8,12

    float acc[4][4];
    #pragma unroll
    for (int i = 0; i < 4; ++i)
        #pragma unroll
        for (int j = 0; j < 4; ++j) acc[i][j] = 0.f;

    for (int k0 = 0; k0 < K; k0 += TK) {
        // load A tile (guard M)
        {
            const int gm = m0 + lrow;
            float4 v = make_float4(0.f, 0.f, 0.f, 0.f);
            if (gm < M)
                v = *(const float4*)(A + (size_t)gm * K + k0 + lcol);
            As[lrow][lcol + 0] = v.x;
            As[lrow][lcol + 1] = v.y;
            As[lrow][lcol + 2] = v.z;
            As[lrow][lcol + 3] = v.w;
        }
        // load W tile (N multiple of 64 -> no guard)
        {
            const int gn = n0 + lrow;
            float4 v = *(const float4*)(W + (size_t)gn * K + k0 + lcol);
            Ws[lrow][lcol + 0] = v.x;
            Ws[lrow][lcol + 1] = v.y;
            Ws[lrow][lcol + 2] = v.z;
            Ws[lrow][lcol + 3] = v.w;
        }
        __syncthreads();

        #pragma unroll
        for (int kk = 0; kk < TK; ++kk) {
            float a[4], w[4];
            #pragma unroll
            for (int i = 0; i < 4; ++i) a[i] = As[ty * 4 + i][kk];
            #pragma unroll
            for (int j = 0; j < 4; ++j) w[j] = Ws[tx * 4 + j][kk];
            #pragma unroll
            for (int i = 0; i < 4; ++i)
                #pragma unroll
                for (int j = 0; j < 4; ++j)
                    acc[i][j] += a[i] * w[j];
        }
        __syncthreads();
    }

    #pragma unroll
    for (int i = 0; i < 4; ++i) {
        const int gm = m0 + ty * 4 + i;
        if (gm >= M) continue;
        #pragma unroll
        for (int j = 0; j < 4; ++j) {
            const int gn = n0 + tx * 4 + j;
            C[(size_t)gm * N + gn] = acc[i][j] + bias[gn];
        }
    }
}

// ---------------------------------------------------------------------------
// RoPE-2D applied in-place to q and k patch rows of the qkv buffer.
// qkv layout: (B, S, 3, H, D) flattened; q at col 0, k at col 512.
// One block per (b,l); 256 threads: h = t>>5, pair p = t&31.
// pair p: p<16 -> angle = (x/1e5) * 10000^(-p/16); p>=16 -> y, p-16.
// out[2p]   = t0*cos - t1*sin
// out[2p+1] = t1*cos + t0*sin
// ---------------------------------------------------------------------------
__global__ __launch_bounds__(256) void rope_kernel(
    float* __restrict__ qkv, const int* __restrict__ coords)
{
    const int bl = blockIdx.x;          // b*L + l
    const int t = threadIdx.x;
    const int h = t >> 5;
    const int p = t & 31;

    const float cx = (float)coords[(size_t)bl * 2 + 0] * 1e-5f;
    const float cy = (float)coords[(size_t)bl * 2 + 1] * 1e-5f;

    const float coord = (p < 16) ? cx : cy;
    const float e = (float)(p < 16 ? p : p - 16);
    const float inv = powf(10000.0f, -e * (1.0f / 16.0f));
    const float ang = coord * inv;
    float sn, cs;
    sincosf(ang, &sn, &cs);

    const int b = bl / L_;
    const int l = bl % L_;
    const size_t row = ((size_t)(b * S_ + 1 + l)) * QKV_COLS;

    float* qp = qkv + row + h * D_ + p * 2;
    const float q0 = qp[0], q1 = qp[1];
    qp[0] = q0 * cs - q1 * sn;
    qp[1] = q1 * cs + q0 * sn;

    float* kp = qkv + row + E_ + h * D_ + p * 2;
    const float k0 = kp[0], k1 = kp[1];
    kp[0] = k0 * cs - k1 * sn;
    kp[1] = k1 * cs + k0 * sn;
}

// ---------------------------------------------------------------------------
// CLS attention: one block per (b,h). Query = row s=0; attends to all S keys.
// Two-pass softmax with scores staged in LDS, then PV with 4 j-groups x 64 d.
// Writes attn_out[b, 0, h*64 + d].
// ---------------------------------------------------------------------------
__global__ __launch_bounds__(256) void cls_attn_kernel(
    const float* __restrict__ qkv, float* __restrict__ attn_out)
{
    const int b = blockIdx.x >> 3;
    const int h = blockIdx.x & 7;
    const int tid = threadIdx.x;

    __shared__ float sc[S_];
    __shared__ float red[256];
    __shared__ float qs[D_];

    const size_t base = (size_t)b * S_ * QKV_COLS;
    if (tid < D_) qs[tid] = qkv[base + h * D_ + tid];
    __syncthreads();

    float lmax = -1e30f;
    for (int j = tid; j < S_; j += 256) {
        const float* krow = qkv + base + (size_t)j * QKV_COLS + E_ + h * D_;
        float s = 0.f;
        #pragma unroll
        for (int d = 0; d < D_; ++d) s += qs[d] * krow[d];
        s *= SCALE;
        sc[j] = s;
        lmax = fmaxf(lmax, s);
    }
    red[tid] = lmax;
    __syncthreads();
    for (int off = 128; off > 0; off >>= 1) {
        if (tid < off) red[tid] = fmaxf(red[tid], red[tid + off]);
        __syncthreads();
    }
    const float m = red[0];
    __syncthreads();

    float lsum = 0.f;
    for (int j = tid; j < S_; j += 256) {
        const float ev = expf(sc[j] - m);
        sc[j] = ev;
        lsum += ev;
    }
    red[tid] = lsum;
    __syncthreads();
    for (int off = 128; off > 0; off >>= 1) {
        if (tid < off) red[tid] += red[tid + off];
        __syncthreads();
    }
    const float denom = red[0];
    __syncthreads();

    const int d = tid & 63;
    const int g = tid >> 6;
    float acc = 0.f;
    for (int j = g; j < S_; j += 4) {
        acc += sc[j] * qkv[base + (size_t)j * QKV_COLS + 2 * E_ + h * D_ + d];
    }
    red[tid] = acc;
    __syncthreads();
    if (g == 0) {
        const float r = red[d] + red[64 + d] + red[128 + d] + red[192 + d];
        attn_out[(size_t)b * S_ * E_ + h * D_ + d] = r / denom;
    }
}

// ---------------------------------------------------------------------------
// Patch attention: one wave (64 lanes) per query (b,h,l). lane = d.
// Keys: cls (s=0) + 9 dilated-window keys l' = l + (w-4)*2 (masked OOB).
// Scores via full-wave shfl_xor reduction; softmax broadcast on all lanes.
// Writes attn_out[b, 1+l, h*64 + d].
// ---------------------------------------------------------------------------
__global__ __launch_bounds__(256) void patch_attn_kernel(
    const float* __restrict__ qkv, float* __restrict__ attn_out)
{
    const int gw = (blockIdx.x * 256 + threadIdx.x) >> 6;  // global wave id
    const int lane = threadIdx.x & 63;

    const int l = gw & (L_ - 1);
    const int bh = gw >> 13;        // L = 2^13
    const int h = bh & 7;
    const int b = bh >> 3;

    const size_t base = (size_t)b * S_ * QKV_COLS;
    const size_t hoff = (size_t)h * D_;

    const float q = qkv[base + (size_t)(1 + l) * QKV_COLS + hoff + lane];

    float s[10];
    {
        float t = q * qkv[base + E_ + hoff + lane];  // cls key (row s=0)
        #pragma unroll
        for (int off = 32; off; off >>= 1) t += __shfl_xor(t, off, 64);
        s[0] = t * SCALE;
    }
    #pragma unroll
    for (int w = 0; w < 9; ++w) {
        const int lp = l + (w - 4) * 2;
        if (lp >= 0 && lp < L_) {
            float t = q * qkv[base + (size_t)(1 + lp) * QKV_COLS + E_ + hoff + lane];
            #pragma unroll
            for (int off = 32; off; off >>= 1) t += __shfl_xor(t, off, 64);
            s[1 + w] = t * SCALE;
        } else {
            s[1 + w] = -1e30f;
        }
    }

    float m = s[0];
    #pragma unroll
    for (int i = 1; i < 10; ++i) m = fmaxf(m, s[i]);
    float p[10];
    float sum = 0.f;
    #pragma unroll
    for (int i = 0; i < 10; ++i) {
        p[i] = expf(s[i] - m);
        sum += p[i];
    }

    float acc = p[0] * qkv[base + 2 * E_ + hoff + lane];  // cls value
    #pragma unroll
    for (int w = 0; w < 9; ++w) {
        const int lp = l + (w - 4) * 2;
        if (lp >= 0 && lp < L_) {
            acc += p[1 + w] * qkv[base + (size_t)(1 + lp) * QKV_COLS + 2 * E_ + hoff + lane];
        }
    }

    attn_out[(size_t)b * S_ * E_ + (size_t)(1 + l) * E_ + hoff + lane] = acc / sum;
}

// ---------------------------------------------------------------------------
// Launch
// ---------------------------------------------------------------------------
extern "C" void kernel_launch(void* const* d_in, const int* in_sizes, int n_in,
                              void* d_out, int out_size, void* d_ws, size_t ws_size,
                              hipStream_t stream)
{
    const float* x      = (const float*)d_in[0];
    const int*   coords = (const int*)  d_in[1];
    const float* w_qkv  = (const float*)d_in[2];
    const float* b_qkv  = (const float*)d_in[3];
    const float* w_out  = (const float*)d_in[4];
    const float* b_out  = (const float*)d_in[5];
    float* out = (float*)d_out;

    const int M = B_ * S_;  // 16386

    float* qkv  = (float*)d_ws;                       // M x 1536
    float* attn = qkv + (size_t)M * QKV_COLS;         // M x 512

    // 1. QKV projection: qkv = x @ w_qkv^T + b_qkv
    {
        dim3 grid(QKV_COLS / TN, (M + TM - 1) / TM);
        gemm_nt_bias<<<grid, 256, 0, stream>>>(x, w_qkv, b_qkv, qkv, M, QKV_COLS, E_);
    }

    // 2. RoPE-2D on q,k patch rows (in place)
    rope_kernel<<<B_ * L_, 256, 0, stream>>>(qkv, coords);

    // 3. CLS attention (rows s=0)
    cls_attn_kernel<<<B_ * H_, 256, 0, stream>>>(qkv, attn);

    // 4. Patch windowed attention (rows s=1..L)
    patch_attn_kernel<<<(B_ * H_ * L_) / 4, 256, 0, stream>>>(qkv, attn);

    // 5. Output projection: out = attn @ w_out^T + b_out
    {
        dim3 grid(E_ / TN, (M + TM - 1) / TM);
        gemm_nt_bias<<<grid, 256, 0, stream>>>(attn, w_out, b_out, out, M, E_, E_);
    }
}

// Round 2
// 262.033 us; speedup vs baseline: 5.4419x; 5.4419x over previous
//
#include <hip/hip_runtime.h>
#include <math.h>

// Problem constants
#define B_ 2
#define S_ 8193
#define L_ 8192
#define E_ 512
#define H_ 8
#define D_ 64
#define QKV_COLS 1536   // 3*E
#define SCALE 0.125f
#define M_ROWS 16386    // B*S
#define M_PAD 16512     // round up to 128

typedef unsigned short u16;
typedef __attribute__((ext_vector_type(8))) short bf16x8;
typedef __attribute__((ext_vector_type(4))) float f32x4;

__device__ __forceinline__ u16 f2bf(float f) {
    unsigned u = __float_as_uint(f);
    unsigned r = (u + 0x7fffu + ((u >> 16) & 1u)) >> 16;   // RNE
    return (u16)r;
}

__device__ __forceinline__ void gload_lds16(const void* g, void* l) {
    __builtin_amdgcn_global_load_lds(
        (const __attribute__((address_space(1))) void*)g,
        (__attribute__((address_space(3))) void*)l, 16, 0, 0);
}

// ---------------------------------------------------------------------------
// float -> bf16 conversion, cols hardcoded 512, zero-pads rows >= rows.
// one thread = 4 elements. total4 = rows_pad*512/4
// ---------------------------------------------------------------------------
__global__ __launch_bounds__(256) void convert_bf16_512(
    const float* __restrict__ src, u16* __restrict__ dst, int rows, long total4)
{
    const long i = (long)blockIdx.x * 256 + threadIdx.x;
    if (i >= total4) return;
    const long f = i * 4;
    const long row = f >> 9;
    ushort4 o;
    if (row < rows) {
        const float4 v = *(const float4*)(src + f);
        o.x = f2bf(v.x); o.y = f2bf(v.y); o.z = f2bf(v.z); o.w = f2bf(v.w);
    } else {
        o = make_ushort4(0, 0, 0, 0);
    }
    *(ushort4*)(dst + f) = o;
}

// ---------------------------------------------------------------------------
// bf16 MFMA GEMM (m97 structure): C[m,n] = A[m,:]·W[n,:] + bias[n]
// A: M_pad x K bf16, W: N x K bf16, C: M x N fp32.
// 128x128 tile, BK=32, 4 waves (2x2), each wave 64x64 = 4x4 16x16 frags.
// N % 128 == 0, K % 32 == 0; M guarded on store (A rows padded with zeros).
// ---------------------------------------------------------------------------
__global__ __launch_bounds__(256) void gemm_bf16_mfma(
    const u16* __restrict__ A, const u16* __restrict__ W,
    const float* __restrict__ bias, float* __restrict__ C,
    int M, int N, int K)
{
    __shared__ u16 As[128 * 32];
    __shared__ u16 Bs[128 * 32];

    const int tid  = threadIdx.x;
    const int wid  = tid >> 6;
    const int lane = tid & 63;
    const int m0 = blockIdx.y * 128;
    const int n0 = blockIdx.x * 128;
    const int wm = (wid >> 1) * 64;
    const int wn = (wid & 1) * 64;

    const int srow = lane >> 2;          // 0..15 row within chunk
    const int scol = (lane & 3) * 8;     // bf16 col offset

    const int fr = lane & 15;            // fragment row/col
    const int fq = lane >> 4;            // k-chunk / row-quad

    f32x4 acc[4][4] = {};

    for (int k0 = 0; k0 < K; k0 += 32) {
        // stage A and B tiles: 2 chunks of 16 rows per wave each
        #pragma unroll
        for (int i = 0; i < 2; ++i) {
            const int c = wid * 2 + i;           // 0..7
            const int row = c * 16 + srow;       // 0..127
            gload_lds16(A + (size_t)(m0 + row) * K + k0 + scol, As + c * 16 * 32);
            gload_lds16(W + (size_t)(n0 + row) * K + k0 + scol, Bs + c * 16 * 32);
        }
        __syncthreads();   // vmcnt(0) drain + barrier

        bf16x8 a[4], b[4];
        #pragma unroll
        for (int mi = 0; mi < 4; ++mi)
            a[mi] = *(const bf16x8*)(As + (wm + mi * 16 + fr) * 32 + fq * 8);
        #pragma unroll
        for (int ni = 0; ni < 4; ++ni)
            b[ni] = *(const bf16x8*)(Bs + (wn + ni * 16 + fr) * 32 + fq * 8);
        #pragma unroll
        for (int mi = 0; mi < 4; ++mi)
            #pragma unroll
            for (int ni = 0; ni < 4; ++ni)
                acc[mi][ni] = __builtin_amdgcn_mfma_f32_16x16x32_bf16(
                    a[mi], b[ni], acc[mi][ni], 0, 0, 0);
        __syncthreads();   // compute done before next stage overwrites
    }

    // C/D layout: col = lane&15, row = (lane>>4)*4 + j
    #pragma unroll
    for (int mi = 0; mi < 4; ++mi) {
        #pragma unroll
        for (int j = 0; j < 4; ++j) {
            const int gm = m0 + wm + mi * 16 + fq * 4 + j;
            if (gm >= M) continue;
            #pragma unroll
            for (int ni = 0; ni < 4; ++ni) {
                const int gn = n0 + wn + ni * 16 + fr;
                C[(size_t)gm * N + gn] = acc[mi][ni][j] + bias[gn];
            }
        }
    }
}

// ---------------------------------------------------------------------------
// RoPE-2D in place on q,k patch rows. Block per (b,l); thread = (h, pair p).
// ---------------------------------------------------------------------------
__global__ __launch_bounds__(256) void rope_kernel(
    float* __restrict__ qkv, const int* __restrict__ coords)
{
    const int bl = blockIdx.x;
    const int t = threadIdx.x;
    const int h = t >> 5;
    const int p = t & 31;

    const float cx = (float)coords[(size_t)bl * 2 + 0] * 1e-5f;
    const float cy = (float)coords[(size_t)bl * 2 + 1] * 1e-5f;

    const float coord = (p < 16) ? cx : cy;
    const float e = (float)(p < 16 ? p : p - 16);
    // 10000^(-e/16) = exp2(-e * log2(10000)/16)
    const float inv = exp2f(-0.83048202372184f * e);
    const float ang = coord * inv;
    float sn, cs;
    __sincosf(ang, &sn, &cs);

    const int b = bl / L_;
    const int l = bl % L_;
    const size_t row = ((size_t)(b * S_ + 1 + l)) * QKV_COLS;

    float* qp = qkv + row + h * D_ + p * 2;
    const float q0 = qp[0], q1 = qp[1];
    qp[0] = q0 * cs - q1 * sn;
    qp[1] = q1 * cs + q0 * sn;

    float* kp = qkv + row + E_ + h * D_ + p * 2;
    const float k0 = kp[0], k1 = kp[1];
    kp[0] = k0 * cs - k1 * sn;
    kp[1] = k1 * cs + k0 * sn;
}

// ---------------------------------------------------------------------------
// CLS attention stage 1: flash-style over S chunks.
// grid = B*H*32; block 256 (4 waves, wave = online softmax over its rows).
// part[bh*32+ch] = {m, l, acc[64]} (66 floats)
// ---------------------------------------------------------------------------
#define NCHUNK 32
#define CLS_ROWS 257   // ceil(8193/32)

__global__ __launch_bounds__(256) void cls_attn_stage1(
    const float* __restrict__ qkv, float* __restrict__ part)
{
    const int blk = blockIdx.x;
    const int bh = blk >> 5, ch = blk & 31;
    const int b = bh >> 3, h = bh & 7;
    const int wid = threadIdx.x >> 6, lane = threadIdx.x & 63;
    const size_t base = (size_t)b * S_ * QKV_COLS;

    const float q = qkv[base + h * D_ + lane];

    const int lo = ch * CLS_ROWS;
    const int hi = (lo + CLS_ROWS < S_) ? lo + CLS_ROWS : S_;

    float m = -1e30f, lsum = 0.f, acc = 0.f;
    for (int j = lo + wid; j < hi; j += 4) {
        const size_t roff = base + (size_t)j * QKV_COLS;
        float t = q * qkv[roff + E_ + h * D_ + lane];
        #pragma unroll
        for (int o = 32; o; o >>= 1) t += __shfl_xor(t, o, 64);
        t *= SCALE;
        const float mn = fmaxf(m, t);
        const float corr = __expf(m - mn);
        const float p = __expf(t - mn);
        lsum = lsum * corr + p;
        acc = acc * corr + p * qkv[roff + 2 * E_ + h * D_ + lane];
        m = mn;
    }

    __shared__ float sm[4], sl[4], sacc[4][64];
    if (lane == 0) { sm[wid] = m; sl[wid] = lsum; }
    sacc[wid][lane] = acc;
    __syncthreads();
    if (wid == 0) {
        const float gm = fmaxf(fmaxf(sm[0], sm[1]), fmaxf(sm[2], sm[3]));
        float gl = 0.f, ga = 0.f;
        #pragma unroll
        for (int w = 0; w < 4; ++w) {
            const float c = __expf(sm[w] - gm);
            gl += sl[w] * c;
            ga += sacc[w][lane] * c;
        }
        float* pp = part + ((size_t)bh * NCHUNK + ch) * 66;
        if (lane == 0) { pp[0] = gm; pp[1] = gl; }
        pp[2 + lane] = ga;
    }
}

// stage 2: combine 32 chunks per (b,h). grid = 16 blocks x 64 threads.
__global__ __launch_bounds__(64) void cls_attn_stage2(
    const float* __restrict__ part, u16* __restrict__ attnb)
{
    const int bh = blockIdx.x;
    const int lane = threadIdx.x;
    const int b = bh >> 3, h = bh & 7;
    float gm = -1e30f;
    for (int c = 0; c < NCHUNK; ++c)
        gm = fmaxf(gm, part[((size_t)bh * NCHUNK + c) * 66]);
    float gl = 0.f, ga = 0.f;
    for (int c = 0; c < NCHUNK; ++c) {
        const float* pp = part + ((size_t)bh * NCHUNK + c) * 66;
        const float w = __expf(pp[0] - gm);
        gl += pp[1] * w;
        ga += pp[2 + lane] * w;
    }
    attnb[(size_t)(b * S_) * E_ + h * D_ + lane] = f2bf(ga / gl);
}

// ---------------------------------------------------------------------------
// Patch attention, LDS-tiled: block per (b,h,64-query tile).
// k/v rows [l0-8, l0+71] staged in LDS; wave per query (lane = d).
// ---------------------------------------------------------------------------
__global__ __launch_bounds__(256) void patch_attn_tiled(
    const float* __restrict__ qkv, u16* __restrict__ attnb)
{
    const int blk = blockIdx.x;
    const int qt = blk & 127;
    const int h = (blk >> 7) & 7;
    const int b = blk >> 10;
    const int l0 = qt * 64;
    const size_t base = (size_t)b * S_ * QKV_COLS;
    const size_t hoff = (size_t)h * D_;

    __shared__ float kb[80][64];
    __shared__ float vb[80][64];
    __shared__ float kc[64], vc[64];

    const int tid = threadIdx.x;
    if (tid < 64) kc[tid] = qkv[base + E_ + hoff + tid];
    else if (tid < 128) vc[tid - 64] = qkv[base + 2 * E_ + hoff + (tid - 64)];

    for (int f = tid; f < 80 * 64; f += 256) {
        const int r = f >> 6, d = f & 63;
        const int lg = l0 - 8 + r;
        float kv = 0.f, vv = 0.f;
        if (lg >= 0 && lg < L_) {
            const size_t roff = base + (size_t)(1 + lg) * QKV_COLS;
            kv = qkv[roff + E_ + hoff + d];
            vv = qkv[roff + 2 * E_ + hoff + d];
        }
        kb[r][d] = kv;
        vb[r][d] = vv;
    }
    __syncthreads();

    const int wid = tid >> 6, lane = tid & 63;
    for (int qi = wid; qi < 64; qi += 4) {
        const int l = l0 + qi;
        const float q = qkv[base + (size_t)(1 + l) * QKV_COLS + hoff + lane];

        float s[10];
        {
            float t = q * kc[lane];
            #pragma unroll
            for (int o = 32; o; o >>= 1) t += __shfl_xor(t, o, 64);
            s[0] = t * SCALE;
        }
        #pragma unroll
        for (int wi = 0; wi < 9; ++wi) {
            const int lp = l + (wi - 4) * 2;
            float t = q * kb[qi + 2 * wi][lane];
            #pragma unroll
            for (int o = 32; o; o >>= 1) t += __shfl_xor(t, o, 64);
            s[1 + wi] = (lp >= 0 && lp < L_) ? t * SCALE : -1e30f;
        }

        float m = s[0];
        #pragma unroll
        for (int i = 1; i < 10; ++i) m = fmaxf(m, s[i]);
        float p[10], sum = 0.f;
        #pragma unroll
        for (int i = 0; i < 10; ++i) { p[i] = __expf(s[i] - m); sum += p[i]; }

        float acc = p[0] * vc[lane];
        #pragma unroll
        for (int wi = 0; wi < 9; ++wi)
            acc += p[1 + wi] * vb[qi + 2 * wi][lane];

        attnb[(size_t)(b * S_ + 1 + l) * E_ + hoff + lane] = f2bf(acc / sum);
    }
}

// ---------------------------------------------------------------------------
// Launch
// ---------------------------------------------------------------------------
extern "C" void kernel_launch(void* const* d_in, const int* in_sizes, int n_in,
                              void* d_out, int out_size, void* d_ws, size_t ws_size,
                              hipStream_t stream)
{
    const float* x      = (const float*)d_in[0];
    const int*   coords = (const int*)  d_in[1];
    const float* w_qkv  = (const float*)d_in[2];
    const float* b_qkv  = (const float*)d_in[3];
    const float* w_out  = (const float*)d_in[4];
    const float* b_out  = (const float*)d_in[5];
    float* out = (float*)d_out;

    // workspace layout
    float* qkv   = (float*)d_ws;                                  // M_ROWS x 1536 f32
    u16*   xb    = (u16*)(qkv + (size_t)M_ROWS * QKV_COLS);       // M_PAD x 512 bf16
    u16*   attnb = xb;                                            // alias (x dead after qkv GEMM)
    u16*   wqb   = xb + (size_t)M_PAD * E_;                       // 1536 x 512
    u16*   wob   = wqb + (size_t)QKV_COLS * E_;                   // 512 x 512
    float* part  = (float*)(wob + (size_t)E_ * E_);               // 16*32*66 floats

    // 1. convert inputs to bf16
    {
        const long t4x = (long)M_PAD * E_ / 4;
        convert_bf16_512<<<(t4x + 255) / 256, 256, 0, stream>>>(x, xb, M_ROWS, t4x);
        const long t4q = (long)QKV_COLS * E_ / 4;
        convert_bf16_512<<<(t4q + 255) / 256, 256, 0, stream>>>(w_qkv, wqb, QKV_COLS, t4q);
        const long t4o = (long)E_ * E_ / 4;
        convert_bf16_512<<<(t4o + 255) / 256, 256, 0, stream>>>(w_out, wob, E_, t4o);
    }

    // 2. QKV projection (bf16 MFMA, fp32 out)
    {
        dim3 grid(QKV_COLS / 128, M_PAD / 128);
        gemm_bf16_mfma<<<grid, 256, 0, stream>>>(xb, wqb, b_qkv, qkv, M_ROWS, QKV_COLS, E_);
    }

    // 3. RoPE-2D in place
    rope_kernel<<<B_ * L_, 256, 0, stream>>>(qkv, coords);

    // 4. CLS attention (split-S flash)
    cls_attn_stage1<<<B_ * H_ * NCHUNK, 256, 0, stream>>>(qkv, part);
    cls_attn_stage2<<<B_ * H_, 64, 0, stream>>>(part, attnb);

    // 5. Patch windowed attention (LDS tiled)
    patch_attn_tiled<<<B_ * H_ * (L_ / 64), 256, 0, stream>>>(qkv, attnb);

    // 6. zero pad rows of attnb, then output projection
    hipMemsetAsync(attnb + (size_t)M_ROWS * E_, 0,
                   (size_t)(M_PAD - M_ROWS) * E_ * sizeof(u16), stream);
    {
        dim3 grid(E_ / 128, M_PAD / 128);
        gemm_bf16_mfma<<<grid, 256, 0, stream>>>(attnb, wob, b_out, out, M_ROWS, E_, E_);
    }
}

// Round 3
// 168.678 us; speedup vs baseline: 8.4537x; 1.5534x over previous
//
#include <hip/hip_runtime.h>
#include <math.h>

// Problem constants
#define B_ 2
#define S_ 8193
#define L_ 8192
#define E_ 512
#define H_ 8
#define D_ 64
#define QKV_COLS 1536   // 3*E
#define SCALE 0.125f
#define M_ROWS 16386    // B*S
#define M_PAD 16512     // round up to 128

typedef unsigned short u16;
typedef __attribute__((ext_vector_type(8))) short bf16x8;
typedef __attribute__((ext_vector_type(8))) unsigned short u16x8;
typedef __attribute__((ext_vector_type(4))) float f32x4;

__device__ __forceinline__ u16 f2bf(float f) {
    unsigned u = __float_as_uint(f);
    unsigned r = (u + 0x7fffu + ((u >> 16) & 1u)) >> 16;   // RNE
    return (u16)r;
}
__device__ __forceinline__ float bf2f(u16 h) {
    return __uint_as_float((unsigned)h << 16);
}

__device__ __forceinline__ void gload_lds16(const void* g, void* l) {
    __builtin_amdgcn_global_load_lds(
        (const __attribute__((address_space(1))) void*)g,
        (__attribute__((address_space(3))) void*)l, 16, 0, 0);
}

// ---------------------------------------------------------------------------
// float -> bf16 conversion, 512 cols, zero-pads rows >= rows.
// ---------------------------------------------------------------------------
__global__ __launch_bounds__(256) void convert_bf16_512(
    const float* __restrict__ src, u16* __restrict__ dst, int rows, long total4)
{
    const long i = (long)blockIdx.x * 256 + threadIdx.x;
    if (i >= total4) return;
    const long f = i * 4;
    const long row = f >> 9;
    ushort4 o;
    if (row < rows) {
        const float4 v = *(const float4*)(src + f);
        o.x = f2bf(v.x); o.y = f2bf(v.y); o.z = f2bf(v.z); o.w = f2bf(v.w);
    } else {
        o = make_ushort4(0, 0, 0, 0);
    }
    *(ushort4*)(dst + f) = o;
}

// ---------------------------------------------------------------------------
// bf16 MFMA GEMM: C = A @ W^T + bias.
// MODE 0: C fp32, plain.   MODE 1: C bf16, fused RoPE-2D on q/k patch rows.
// 128x128 tile, BK=32, 4 waves (2x2), wave = 64x64 = 4x4 16x16x32 frags.
// ---------------------------------------------------------------------------
template <int MODE>
__global__ __launch_bounds__(256) void gemm_bf16_mfma(
    const u16* __restrict__ A, const u16* __restrict__ W,
    const float* __restrict__ bias, void* __restrict__ Cv,
    const int* __restrict__ coords, int M, int N, int K)
{
    __shared__ u16 As[128 * 32];
    __shared__ u16 Bs[128 * 32];

    const int tid  = threadIdx.x;
    const int wid  = tid >> 6;
    const int lane = tid & 63;
    const int m0 = blockIdx.y * 128;
    const int n0 = blockIdx.x * 128;
    const int wm = (wid >> 1) * 64;
    const int wn = (wid & 1) * 64;

    const int srow = lane >> 2;
    const int scol = (lane & 3) * 8;
    const int fr = lane & 15;
    const int fq = lane >> 4;

    f32x4 acc[4][4] = {};

    for (int k0 = 0; k0 < K; k0 += 32) {
        #pragma unroll
        for (int i = 0; i < 2; ++i) {
            const int c = wid * 2 + i;
            const int row = c * 16 + srow;
            gload_lds16(A + (size_t)(m0 + row) * K + k0 + scol, As + c * 16 * 32);
            gload_lds16(W + (size_t)(n0 + row) * K + k0 + scol, Bs + c * 16 * 32);
        }
        __syncthreads();

        bf16x8 a[4], b[4];
        #pragma unroll
        for (int mi = 0; mi < 4; ++mi)
            a[mi] = *(const bf16x8*)(As + (wm + mi * 16 + fr) * 32 + fq * 8);
        #pragma unroll
        for (int ni = 0; ni < 4; ++ni)
            b[ni] = *(const bf16x8*)(Bs + (wn + ni * 16 + fr) * 32 + fq * 8);
        #pragma unroll
        for (int mi = 0; mi < 4; ++mi)
            #pragma unroll
            for (int ni = 0; ni < 4; ++ni)
                acc[mi][ni] = __builtin_amdgcn_mfma_f32_16x16x32_bf16(
                    a[mi], b[ni], acc[mi][ni], 0, 0, 0);
        __syncthreads();
    }

    if (MODE == 0) {
        float* C = (float*)Cv;
        #pragma unroll
        for (int mi = 0; mi < 4; ++mi)
            #pragma unroll
            for (int j = 0; j < 4; ++j) {
                const int gm = m0 + wm + mi * 16 + fq * 4 + j;
                if (gm >= M) continue;
                #pragma unroll
                for (int ni = 0; ni < 4; ++ni) {
                    const int gn = n0 + wn + ni * 16 + fr;
                    C[(size_t)gm * N + gn] = acc[mi][ni][j] + bias[gn];
                }
            }
    } else {
        u16* C = (u16*)Cv;
        const bool rope_blk = (n0 < 2 * E_);   // q or k column tiles
        #pragma unroll
        for (int mi = 0; mi < 4; ++mi) {
            #pragma unroll
            for (int j = 0; j < 4; ++j) {
                const int gm = m0 + wm + mi * 16 + fq * 4 + j;
                const bool mok = gm < M;
                int b = 0, s = gm;
                if (gm >= S_) { b = 1; s = gm - S_; }
                const bool rot = rope_blk && mok && (s > 0);
                float cx = 0.f, cy = 0.f;
                if (rot) {
                    const int l = s - 1;
                    cx = (float)coords[((size_t)(b * L_ + l)) * 2 + 0] * 1e-5f;
                    cy = (float)coords[((size_t)(b * L_ + l)) * 2 + 1] * 1e-5f;
                }
                #pragma unroll
                for (int ni = 0; ni < 4; ++ni) {
                    const int gn = n0 + wn + ni * 16 + fr;
                    float v = acc[mi][ni][j] + bias[gn];
                    const float partner = __shfl_xor(v, 1, 64);  // gn^1 lives in lane^1
                    if (rot) {
                        const int p2 = (gn & 63) >> 1;
                        const float coord = (p2 < 16) ? cx : cy;
                        const float inv = exp2f(-0.83048202372184f * (float)(p2 & 15));
                        float sn, cs;
                        __sincosf(coord * inv, &sn, &cs);
                        v = (gn & 1) ? (v * cs + partner * sn)
                                     : (v * cs - partner * sn);
                    }
                    if (mok) C[(size_t)gm * N + gn] = f2bf(v);
                }
            }
        }
    }
}

// ---------------------------------------------------------------------------
// CLS attention stage 1 (bf16 qkv): flash over S chunks.
// grid = B*H*64; block 256 (4 waves).
// ---------------------------------------------------------------------------
#define NCHUNK 64
#define CLS_ROWS 129   // ceil(8193/64)

__global__ __launch_bounds__(256) void cls_attn_stage1(
    const u16* __restrict__ qkvb, float* __restrict__ part)
{
    const int blk = blockIdx.x;
    const int bh = blk >> 6, ch = blk & 63;
    const int b = bh >> 3, h = bh & 7;
    const int wid = threadIdx.x >> 6, lane = threadIdx.x & 63;
    const size_t base = (size_t)b * S_ * QKV_COLS;

    const float q = bf2f(qkvb[base + h * D_ + lane]);

    const int lo = ch * CLS_ROWS;
    const int hi = (lo + CLS_ROWS < S_) ? lo + CLS_ROWS : S_;

    float m = -1e30f, lsum = 0.f, acc = 0.f;
    for (int j = lo + wid; j < hi; j += 4) {
        const size_t roff = base + (size_t)j * QKV_COLS;
        float t = q * bf2f(qkvb[roff + E_ + h * D_ + lane]);
        #pragma unroll
        for (int o = 32; o; o >>= 1) t += __shfl_xor(t, o, 64);
        t *= SCALE;
        const float mn = fmaxf(m, t);
        const float corr = __expf(m - mn);
        const float p = __expf(t - mn);
        lsum = lsum * corr + p;
        acc = acc * corr + p * bf2f(qkvb[roff + 2 * E_ + h * D_ + lane]);
        m = mn;
    }

    __shared__ float sm[4], sl[4], sacc[4][64];
    if (lane == 0) { sm[wid] = m; sl[wid] = lsum; }
    sacc[wid][lane] = acc;
    __syncthreads();
    if (wid == 0) {
        const float gm = fmaxf(fmaxf(sm[0], sm[1]), fmaxf(sm[2], sm[3]));
        float gl = 0.f, ga = 0.f;
        #pragma unroll
        for (int w = 0; w < 4; ++w) {
            const float c = __expf(sm[w] - gm);
            gl += sl[w] * c;
            ga += sacc[w][lane] * c;
        }
        float* pp = part + ((size_t)bh * NCHUNK + ch) * 66;
        if (lane == 0) { pp[0] = gm; pp[1] = gl; }
        pp[2 + lane] = ga;
    }
}

__global__ __launch_bounds__(64) void cls_attn_stage2(
    const float* __restrict__ part, u16* __restrict__ attnb)
{
    const int bh = blockIdx.x;
    const int lane = threadIdx.x;
    const int b = bh >> 3, h = bh & 7;
    float gm = -1e30f;
    for (int c = 0; c < NCHUNK; ++c)
        gm = fmaxf(gm, part[((size_t)bh * NCHUNK + c) * 66]);
    float gl = 0.f, ga = 0.f;
    for (int c = 0; c < NCHUNK; ++c) {
        const float* pp = part + ((size_t)bh * NCHUNK + c) * 66;
        const float w = __expf(pp[0] - gm);
        gl += pp[1] * w;
        ga += pp[2 + lane] * w;
    }
    attnb[(size_t)(b * S_) * E_ + h * D_ + lane] = f2bf(ga / gl);
}

// ---------------------------------------------------------------------------
// Patch attention: lane = query, no cross-lane ops.
// Block = 128 threads (2 waves) = 128 queries. K then V staged sequentially
// in one XOR-swizzled LDS buffer (144 rows x 128B). p[10] live in regs.
// ---------------------------------------------------------------------------
#define PQT 128

__global__ __launch_bounds__(128) void patch_attn(
    const u16* __restrict__ qkvb, u16* __restrict__ attnb)
{
    const int blk = blockIdx.x;
    const int qt = blk & 63;
    const int h = (blk >> 6) & 7;
    const int b = blk >> 9;
    const int l0 = qt * PQT;
    const size_t base = (size_t)b * S_ * QKV_COLS;   // u16 units
    const int hoff = h * D_;

    __shared__ u16 kv[144 * 64];
    __shared__ float kc[64], vc[64];

    const int t = threadIdx.x;

    if (t < 64) kc[t] = bf2f(qkvb[base + E_ + hoff + t]);
    else        vc[t - 64] = bf2f(qkvb[base + 2 * E_ + hoff + (t - 64)]);

    // ---- stage K rows l0-8 .. l0+135 (swizzled chunks) ----
    #pragma unroll
    for (int i = 0; i < 9; ++i) {
        const int ci = i * 128 + t;
        const int r = ci >> 3, c = ci & 7;
        const int lg = l0 - 8 + r;
        u16x8 v = {};
        if (lg >= 0 && lg < L_)
            v = *(const u16x8*)(qkvb + base + (size_t)(1 + lg) * QKV_COLS + E_ + hoff + c * 8);
        *(u16x8*)(kv + r * 64 + ((c ^ (r & 7)) * 8)) = v;
    }
    __syncthreads();

    const int l = l0 + t;
    const size_t qrow = base + (size_t)(1 + l) * QKV_COLS + hoff;

    float s[10];
    #pragma unroll
    for (int w = 0; w < 10; ++w) s[w] = 0.f;

    #pragma unroll
    for (int c = 0; c < 8; ++c) {
        const u16x8 qv = *(const u16x8*)(qkvb + qrow + c * 8);
        float qf[8];
        #pragma unroll
        for (int i = 0; i < 8; ++i) qf[i] = bf2f(qv[i]);
        #pragma unroll
        for (int i = 0; i < 8; ++i) s[0] += qf[i] * kc[c * 8 + i];
        #pragma unroll
        for (int w = 0; w < 9; ++w) {
            const int kr = t + 2 * w;
            const u16x8 kk = *(const u16x8*)(kv + kr * 64 + ((c ^ (kr & 7)) * 8));
            #pragma unroll
            for (int i = 0; i < 8; ++i) s[1 + w] += qf[i] * bf2f(kk[i]);
        }
    }

    // softmax (10 logits, in-bounds masking)
    s[0] *= SCALE;
    #pragma unroll
    for (int w = 0; w < 9; ++w) {
        const int lp = l + 2 * w - 8;
        s[1 + w] = (lp >= 0 && lp < L_) ? s[1 + w] * SCALE : -1e30f;
    }
    float m = s[0];
    #pragma unroll
    for (int w = 1; w < 10; ++w) m = fmaxf(m, s[w]);
    float sum = 0.f;
    #pragma unroll
    for (int w = 0; w < 10; ++w) { s[w] = __expf(s[w] - m); sum += s[w]; }
    const float rsum = 1.0f / sum;

    // ---- restage V over K ----
    __syncthreads();
    #pragma unroll
    for (int i = 0; i < 9; ++i) {
        const int ci = i * 128 + t;
        const int r = ci >> 3, c = ci & 7;
        const int lg = l0 - 8 + r;
        u16x8 v = {};
        if (lg >= 0 && lg < L_)
            v = *(const u16x8*)(qkvb + base + (size_t)(1 + lg) * QKV_COLS + 2 * E_ + hoff + c * 8);
        *(u16x8*)(kv + r * 64 + ((c ^ (r & 7)) * 8)) = v;
    }
    __syncthreads();

    // ---- PV ----
    const size_t orow = (size_t)(b * S_ + 1 + l) * E_ + hoff;
    #pragma unroll
    for (int c = 0; c < 8; ++c) {
        float acc[8];
        #pragma unroll
        for (int i = 0; i < 8; ++i) acc[i] = s[0] * vc[c * 8 + i];
        #pragma unroll
        for (int w = 0; w < 9; ++w) {
            const int vr = t + 2 * w;
            const u16x8 vv = *(const u16x8*)(kv + vr * 64 + ((c ^ (vr & 7)) * 8));
            #pragma unroll
            for (int i = 0; i < 8; ++i) acc[i] += s[1 + w] * bf2f(vv[i]);
        }
        u16x8 o;
        #pragma unroll
        for (int i = 0; i < 8; ++i) o[i] = f2bf(acc[i] * rsum);
        *(u16x8*)(attnb + orow + c * 8) = o;
    }
}

// ---------------------------------------------------------------------------
// Launch
// ---------------------------------------------------------------------------
extern "C" void kernel_launch(void* const* d_in, const int* in_sizes, int n_in,
                              void* d_out, int out_size, void* d_ws, size_t ws_size,
                              hipStream_t stream)
{
    const float* x      = (const float*)d_in[0];
    const int*   coords = (const int*)  d_in[1];
    const float* w_qkv  = (const float*)d_in[2];
    const float* b_qkv  = (const float*)d_in[3];
    const float* w_out  = (const float*)d_in[4];
    const float* b_out  = (const float*)d_in[5];
    float* out = (float*)d_out;

    // workspace layout (all bf16 except part)
    u16*   qkvb  = (u16*)d_ws;                                // M_ROWS x 1536
    u16*   xb    = qkvb + (size_t)M_ROWS * QKV_COLS;          // M_PAD x 512
    u16*   attnb = xb;                                        // alias (x dead after qkv GEMM)
    u16*   wqb   = xb + (size_t)M_PAD * E_;                   // 1536 x 512
    u16*   wob   = wqb + (size_t)QKV_COLS * E_;               // 512 x 512
    float* part  = (float*)(wob + (size_t)E_ * E_);           // 16*64*66 floats

    // 1. convert inputs to bf16
    {
        const long t4x = (long)M_PAD * E_ / 4;
        convert_bf16_512<<<(t4x + 255) / 256, 256, 0, stream>>>(x, xb, M_ROWS, t4x);
        const long t4q = (long)QKV_COLS * E_ / 4;
        convert_bf16_512<<<(t4q + 255) / 256, 256, 0, stream>>>(w_qkv, wqb, QKV_COLS, t4q);
        const long t4o = (long)E_ * E_ / 4;
        convert_bf16_512<<<(t4o + 255) / 256, 256, 0, stream>>>(w_out, wob, E_, t4o);
    }

    // 2. QKV projection + fused RoPE, bf16 out
    {
        dim3 grid(QKV_COLS / 128, M_PAD / 128);
        gemm_bf16_mfma<1><<<grid, 256, 0, stream>>>(
            xb, wqb, b_qkv, qkvb, coords, M_ROWS, QKV_COLS, E_);
    }

    // 3. CLS attention
    cls_attn_stage1<<<B_ * H_ * NCHUNK, 256, 0, stream>>>(qkvb, part);
    cls_attn_stage2<<<B_ * H_, 64, 0, stream>>>(part, attnb);

    // 4. Patch windowed attention
    patch_attn<<<B_ * H_ * (L_ / PQT), PQT, 0, stream>>>(qkvb, attnb);

    // 5. Output projection (fp32 out)
    {
        dim3 grid(E_ / 128, M_PAD / 128);
        gemm_bf16_mfma<0><<<grid, 256, 0, stream>>>(
            attnb, wob, b_out, out, nullptr, M_ROWS, E_, E_);
    }
}